// Round 9
// baseline (48.413 us; speedup 1.0000x reference)
//
#include <hip/hip_runtime.h>

#define N_RBF 16
#define N_HIDDEN 32
#define BLOCK 256                 // 4 waves: wave = (atom in {0,1}) x (half-range in {0,1})
#define NW 4
#define DEPTH 16                  // per-lane private queue depth (mu ~5, +overflow fallback)

// Gaussian-grid recurrence (a = 4.5, w = 1/3):
//   r_k = exp(-a (d - k w)^2); r_0 = exp(-a d^2); r_{k+1} = r_k * s_k,
//   s_k = exp(3d - 0.5 - k).  Even/odd split for ILP.
// Chain scaled by 2^80 so r_0 never underflows for d < 5.
#define LOG2E 1.44269504088896340736f
#define NC   (-4.5f * LOG2E)
#define S0A  (3.0f * LOG2E)
#define S0B  (-0.5f * LOG2E)
#define BIAS 80.0f
#define UNSC 8.271806125530277e-25f     // 2^-80
#define C_E1 0.36787944117144233f       // e^-1
#define C_E3 0.049787068367863944f      // e^-3
#define C_E4 0.018315638888734179f      // e^-4

__device__ __forceinline__ float rfl(float x) {
    return __int_as_float(__builtin_amdgcn_readfirstlane(__float_as_int(x)));
}

// Accumulate via inline-asm v_add_f32: pins feat[] to arch VGPRs (no AGPR/scratch
// demotion -- the R4-R8 regression), single VALU op per accumulate.
__device__ __forceinline__ void rbf_batch(float d2, bool active, float (&feat)[N_RBF]) {
    d2 = active ? d2 : 1.0f;          // masked lanes: benign arg, no inf/NaN
    float d  = __builtin_amdgcn_sqrtf(d2);
    float r0 = __builtin_amdgcn_exp2f(fmaf(d2, NC, BIAS));   // 2^80 * exp(-a d^2)
    float s  = __builtin_amdgcn_exp2f(fmaf(d, S0A, S0B));    // exp(3d - 0.5)
    float r1 = r0 * s;
    if (!active) { r0 = 0.0f; r1 = 0.0f; }
    float s2 = s * s;
    float ue = s2 * C_E1;
    float uo = s2 * C_E3;
    #pragma unroll
    for (int k = 0; k < N_RBF; k += 2) {
        asm volatile("v_add_f32 %0, %0, %1" : "+v"(feat[k])     : "v"(r0));
        asm volatile("v_add_f32 %0, %0, %1" : "+v"(feat[k + 1]) : "v"(r1));
        r0 *= ue;  r1 *= uo;
        ue *= C_E4; uo *= C_E4;
    }
}

// Transpose-reduce 16 per-lane partials across 64 lanes.
// Lanes with (lane&3)==0 return the wave-sum of feature k=(lane>>2).
__device__ __forceinline__ float treduce(float (&f)[N_RBF], int lane) {
    float w1r[8];
    #pragma unroll
    for (int k = 0; k < 8; ++k) {
        float lo = f[k], hi = f[k + 8];
        float lo2 = __shfl_xor(lo, 32, 64);
        float hi2 = __shfl_xor(hi, 32, 64);
        w1r[k] = (lane & 32) ? (hi + hi2) : (lo + lo2);
    }
    float w2r[4];
    #pragma unroll
    for (int k = 0; k < 4; ++k) {
        float lo = w1r[k], hi = w1r[k + 4];
        float lo2 = __shfl_xor(lo, 16, 64);
        float hi2 = __shfl_xor(hi, 16, 64);
        w2r[k] = (lane & 16) ? (hi + hi2) : (lo + lo2);
    }
    float w3r[2];
    #pragma unroll
    for (int k = 0; k < 2; ++k) {
        float lo = w2r[k], hi = w2r[k + 2];
        float lo2 = __shfl_xor(lo, 8, 64);
        float hi2 = __shfl_xor(hi, 8, 64);
        w3r[k] = (lane & 8) ? (hi + hi2) : (lo + lo2);
    }
    float lo2 = __shfl_xor(w3r[0], 4, 64);
    float hi2 = __shfl_xor(w3r[1], 4, 64);
    float w4 = (lane & 4) ? (w3r[1] + hi2) : (w3r[0] + lo2);
    w4 += __shfl_xor(w4, 2, 64);
    w4 += __shfl_xor(w4, 1, 64);
    return w4;
}

__global__ __launch_bounds__(256)
void pack_kernel(const float* __restrict__ pos, float4* __restrict__ ppos,
                 float* __restrict__ out, int n, int npad)
{
    int i = blockIdx.x * 256 + threadIdx.x;
    if (i == 0) out[0] = 0.0f;
    if (i < npad) {
        float4 v;
        if (i < n) { v.x = pos[3*i]; v.y = pos[3*i+1]; v.z = pos[3*i+2]; v.w = 0.f; }
        else       { v.x = 1e9f;     v.y = 1e9f;       v.z = 1e9f;       v.w = 0.f; }
        ppos[i] = v;
    }
}

__global__ __launch_bounds__(BLOCK, 4)    // cap 128 VGPR: room for feat[] in arch regs
void ag3sr_main(const float4* __restrict__ ppos,   // [npad] sentinel-padded
                const float* __restrict__ W1,      // [16,32]
                const float* __restrict__ b1,      // [32]
                const float* __restrict__ W2,      // [32]
                const float* __restrict__ b2,      // [1]
                float* __restrict__ out,           // [1]
                int n, int halfr)                  // halfr = npad/2 (mult of 64)
{
    __shared__ float sq[NW][DEPTH][64];    // 16 KB: per-lane private queues
    __shared__ float sfeat[NW][N_RBF];
    __shared__ float sW1[N_RBF * N_HIDDEN];
    __shared__ float sb1[N_HIDDEN], sW2[N_HIDDEN];

    const int tid    = threadIdx.x;
    const int wave   = tid >> 6;
    const int lane   = tid & 63;
    const int a0     = blockIdx.x * 2;         // block owns atoms a0, a0+1
    const int atom   = a0 + (wave >> 1);
    const int halfid = wave & 1;

    for (int idx = tid; idx < N_RBF * N_HIDDEN; idx += BLOCK) sW1[idx] = W1[idx];
    if (tid < N_HIDDEN) { sb1[tid] = b1[tid]; sW2[tid] = W2[tid]; }

    float4 pa = ppos[atom];
    const float xa = rfl(pa.x), ya = rfl(pa.y), za = rfl(pa.z);

    float feat[N_RBF];
    #pragma unroll
    for (int k = 0; k < N_RBF; ++k) feat[k] = 0.0f;

    // ---- Phase A: per-lane queue compaction (no cross-lane ops at all) ----
    const int jb = halfid * halfr;
    const int iters = halfr >> 6;              // 32 for n=4096
    int cnt = 0;                               // per-lane queue count (VGPR)

#define PROC(PJ)                                                              \
    {                                                                         \
        float dx = (PJ).x - xa, dy = (PJ).y - ya, dz = (PJ).z - za;           \
        float q = fmaf(dz, dz, fmaf(dy, dy, dx * dx));                        \
        bool p = (q > 0.0f) & (q < 25.0f);                                    \
        bool room = cnt < DEPTH;                                              \
        if (p & room) sq[wave][cnt][lane] = q;  /* masked, conflict-free */   \
        bool ovf = p & (!room);                                               \
        if (__any(ovf)) rbf_batch(q, ovf, feat);  /* exact, ~never taken */   \
        cnt += (int)(p & room);                                               \
    }

    if (iters >= 2) {
        float4 b0 = ppos[jb + lane];
        float4 b1v = ppos[jb + 64 + lane];
        int it = 2;
        for (; it + 1 < iters; it += 2) {
            float4 n0 = ppos[jb + (it << 6) + lane];         // 2-deep prefetch
            float4 n1 = ppos[jb + ((it + 1) << 6) + lane];
            PROC(b0); PROC(b1v);
            b0 = n0; b1v = n1;
        }
        PROC(b0); PROC(b1v);
        if (iters & 1) { float4 t = ppos[jb + ((iters - 1) << 6) + lane]; PROC(t); }
    } else if (iters == 1) {
        float4 t = ppos[jb + lane]; PROC(t);
    }
#undef PROC

    // ---- Phase B: drain per-lane queues to wave-max depth ----
    {
        int mx = cnt;
        #pragma unroll
        for (int off = 32; off > 0; off >>= 1) {
            int o = __shfl_xor(mx, off, 64);
            mx = mx > o ? mx : o;
        }
        mx = __builtin_amdgcn_readfirstlane(mx);   // scalar loop bound
        for (int s = 0; s < mx; ++s) {
            float qd2 = sq[wave][s][lane];          // stride-1 lanes: conflict-free
            rbf_batch(qd2, s < cnt, feat);
        }
    }

    // ---- Epilogue: wave-reduce, block-combine, MLP, one atomic ----
    float w4 = treduce(feat, lane);
    if ((lane & 3) == 0) sfeat[wave][lane >> 2] = w4;
    __syncthreads();

    if (tid < 64) {                            // wave 0: both atoms' MLP
        const int a = tid >> 5, h = tid & 31;
        const bool valid = (a0 + a) < n;
        float e = 0.0f;
        if (valid) {
            float acc = sb1[h];
            #pragma unroll
            for (int k = 0; k < N_RBF; ++k) {
                float f = (sfeat[a * 2][k] + sfeat[a * 2 + 1][k]) * UNSC;
                acc = fmaf(f, sW1[k * N_HIDDEN + h], acc);
            }
            float sg = 1.0f / (1.0f + __builtin_amdgcn_exp2f(-acc * LOG2E));
            e = acc * sg * sW2[h];
            if (h == 0) e += b2[0];
        }
        #pragma unroll
        for (int off = 16; off > 0; off >>= 1) e += __shfl_xor(e, off, 64);
        e += __shfl_xor(e, 32, 64);            // combine the two atoms
        if (tid == 0) atomicAdd(out, e);
    }
}

extern "C" void kernel_launch(void* const* d_in, const int* in_sizes, int n_in,
                              void* d_out, int out_size, void* d_ws, size_t ws_size,
                              hipStream_t stream) {
    const float* pos = (const float*)d_in[0];
    const float* W1  = (const float*)d_in[1];
    const float* b1  = (const float*)d_in[2];
    const float* W2  = (const float*)d_in[3];
    const float* b2  = (const float*)d_in[4];
    float* out = (float*)d_out;

    const int n     = in_sizes[0] / 3;
    const int npad  = (n + 127) & ~127;     // two halves, each mult of 64
    const int halfr = npad >> 1;

    float4* ppos = (float4*)d_ws;           // 16*npad bytes of scratch

    pack_kernel<<<(npad + 255) / 256, 256, 0, stream>>>(pos, ppos, out, n, npad);

    const int grid = npad / 2;              // 2 atoms per block
    ag3sr_main<<<grid, BLOCK, 0, stream>>>(ppos, W1, b1, W2, b2, out, n, halfr);
}

// Round 10
// 43.448 us; speedup vs baseline: 1.1143x; 1.1143x over previous
//
#include <hip/hip_runtime.h>

typedef float f2 __attribute__((ext_vector_type(2)));

#define N_RBF 16
#define N_HIDDEN 32
#define BLOCK 256                 // 4 waves: wave = (atom in {0,1}) x (half-range in {0,1})
#define NW 4
#define DEPTH 20                  // per-lane queue depth (mean ~5.0 over 32 iters)

// Gaussian-grid recurrence (a = 4.5, w = 1/3):
//   r_k = exp(-a (d - k w)^2); r_0 = exp(-a d^2); r_{k+1} = r_k * s_k,
//   s_k = exp(3d - 0.5 - k).  Even/odd lanes of a float2 run the two
//   interleaved chains: rr=(r_k, r_{k+1}), uu=(s^2 e^-1, s^2 e^-3), uu *= e^-4.
// Chain scaled by 2^80 so r_0 never underflows for d < 5.
#define LOG2E 1.44269504088896340736f
#define NC   (-4.5f * LOG2E)
#define S0A  (3.0f * LOG2E)
#define S0B  (-0.5f * LOG2E)
#define BIAS 80.0f
#define UNSC 8.271806125530277e-25f     // 2^-80
#define C_E1 0.36787944117144233f       // e^-1
#define C_E3 0.049787068367863944f      // e^-3
#define C_E4 0.018315638888734179f      // e^-4

__device__ __forceinline__ float rfl(float x) {
    return __int_as_float(__builtin_amdgcn_readfirstlane(__float_as_int(x)));
}

// Packed even/odd RBF chain: 8x (v_pk_add + v_pk_mul + v_pk_mul).
__device__ __forceinline__ void rbf_f2(float d2, bool active, f2 (&ff)[8]) {
    d2 = active ? d2 : 1.0f;          // masked lanes: benign arg, no inf/NaN
    float d  = __builtin_amdgcn_sqrtf(d2);
    float r0 = __builtin_amdgcn_exp2f(fmaf(d2, NC, BIAS));   // 2^80 * exp(-a d^2)
    float s  = __builtin_amdgcn_exp2f(fmaf(d, S0A, S0B));    // exp(3d - 0.5)
    float r1 = r0 * s;
    if (!active) { r0 = 0.0f; r1 = 0.0f; }
    float s2 = s * s;
    f2 rr; rr.x = r0;       rr.y = r1;
    f2 uu; uu.x = s2 * C_E1; uu.y = s2 * C_E3;
    #pragma unroll
    for (int k = 0; k < 8; ++k) {
        ff[k] += rr;          // v_pk_add_f32
        rr *= uu;             // v_pk_mul_f32
        uu *= C_E4;           // v_pk_mul_f32 (scalar splat)
    }
}

// Transpose-reduce 16 per-lane partials across 64 lanes.
// Lanes with (lane&3)==0 return the wave-sum of feature k=(lane>>2).
__device__ __forceinline__ float treduce(float (&f)[N_RBF], int lane) {
    float w1r[8];
    #pragma unroll
    for (int k = 0; k < 8; ++k) {
        float lo = f[k], hi = f[k + 8];
        float lo2 = __shfl_xor(lo, 32, 64);
        float hi2 = __shfl_xor(hi, 32, 64);
        w1r[k] = (lane & 32) ? (hi + hi2) : (lo + lo2);
    }
    float w2r[4];
    #pragma unroll
    for (int k = 0; k < 4; ++k) {
        float lo = w1r[k], hi = w1r[k + 4];
        float lo2 = __shfl_xor(lo, 16, 64);
        float hi2 = __shfl_xor(hi, 16, 64);
        w2r[k] = (lane & 16) ? (hi + hi2) : (lo + lo2);
    }
    float w3r[2];
    #pragma unroll
    for (int k = 0; k < 2; ++k) {
        float lo = w2r[k], hi = w2r[k + 2];
        float lo2 = __shfl_xor(lo, 8, 64);
        float hi2 = __shfl_xor(hi, 8, 64);
        w3r[k] = (lane & 8) ? (hi + hi2) : (lo + lo2);
    }
    float lo2 = __shfl_xor(w3r[0], 4, 64);
    float hi2 = __shfl_xor(w3r[1], 4, 64);
    float w4 = (lane & 4) ? (w3r[1] + hi2) : (w3r[0] + lo2);
    w4 += __shfl_xor(w4, 2, 64);
    w4 += __shfl_xor(w4, 1, 64);
    return w4;
}

__global__ __launch_bounds__(256)
void pack_kernel(const float* __restrict__ pos, float4* __restrict__ ppos,
                 float* __restrict__ out, int n, int npad)
{
    int i = blockIdx.x * 256 + threadIdx.x;
    if (i == 0) out[0] = 0.0f;
    if (i < npad) {
        float4 v;
        if (i < n) { v.x = pos[3*i]; v.y = pos[3*i+1]; v.z = pos[3*i+2]; v.w = 0.f; }
        else       { v.x = 1e9f;     v.y = 1e9f;       v.z = 1e9f;       v.w = 0.f; }
        ppos[i] = v;
    }
}

__global__ __launch_bounds__(BLOCK)
void ag3sr_main(const float4* __restrict__ ppos,   // [npad] sentinel-padded
                const float* __restrict__ W1,      // [16,32]
                const float* __restrict__ b1,      // [32]
                const float* __restrict__ W2,      // [32]
                const float* __restrict__ b2,      // [1]
                float* __restrict__ out,           // [1]
                int n, int halfr)                  // halfr = npad/2 (iters mult of 4)
{
    __shared__ float sq[NW][DEPTH + 1][64];        // +1: phase-B over-read pad
    __shared__ float sfeat[NW][N_RBF];
    __shared__ float sW1[N_RBF * N_HIDDEN];
    __shared__ float sb1[N_HIDDEN], sW2[N_HIDDEN];

    const int tid    = threadIdx.x;
    const int wave   = tid >> 6;
    const int lane   = tid & 63;
    const int a0     = blockIdx.x * 2;             // block owns atoms a0, a0+1
    const int atom   = a0 + (wave >> 1);
    const int halfid = wave & 1;

    for (int idx = tid; idx < N_RBF * N_HIDDEN; idx += BLOCK) sW1[idx] = W1[idx];
    if (tid < N_HIDDEN) { sb1[tid] = b1[tid]; sW2[tid] = W2[tid]; }

    float4 pa = ppos[atom];
    const float xa = rfl(pa.x), ya = rfl(pa.y), za = rfl(pa.z);

    f2 ff[8];
    #pragma unroll
    for (int k = 0; k < 8; ++k) { ff[k].x = 0.0f; ff[k].y = 0.0f; }

    // ---- Phase A: per-lane queue compaction, 4-deep prefetch, 4-wide ----
    const int jb = halfid * halfr;
    const int iters = halfr >> 6;                  // 32 for n=4096, mult of 4
    int cnt = 0;                                   // per-lane queue count

#define PROC(PJ)                                                              \
    {                                                                         \
        float dx = (PJ).x - xa, dy = (PJ).y - ya, dz = (PJ).z - za;           \
        float q = fmaf(dz, dz, fmaf(dy, dy, dx * dx));                        \
        bool p = (q > 0.0f) & (q < 25.0f);                                    \
        bool room = cnt < DEPTH;                                              \
        if (p & room) sq[wave][cnt][lane] = q;                                \
        bool ovf = p & (!room);                                               \
        if (__builtin_expect(__any((int)ovf), 0)) rbf_f2(q, ovf, ff);         \
        cnt += (int)(p & room);                                               \
    }

    {
        float4 u0 = ppos[jb + 0   + lane];
        float4 u1 = ppos[jb + 64  + lane];
        float4 u2 = ppos[jb + 128 + lane];
        float4 u3 = ppos[jb + 192 + lane];
        int it = 0;
        for (; it + 4 < iters; it += 4) {
            float4 n0 = ppos[jb + ((it + 4) << 6) + lane];   // 4-deep prefetch
            float4 n1 = ppos[jb + ((it + 5) << 6) + lane];
            float4 n2 = ppos[jb + ((it + 6) << 6) + lane];
            float4 n3 = ppos[jb + ((it + 7) << 6) + lane];
            PROC(u0); PROC(u1); PROC(u2); PROC(u3);
            u0 = n0; u1 = n1; u2 = n2; u3 = n3;
        }
        PROC(u0); PROC(u1); PROC(u2); PROC(u3);
    }
#undef PROC

    // ---- Phase B: drain queues, 1-deep pipelined ds_read ----
    {
        int mx = cnt;
        #pragma unroll
        for (int off = 32; off > 0; off >>= 1) {
            int o = __shfl_xor(mx, off, 64);
            mx = mx > o ? mx : o;
        }
        mx = __builtin_amdgcn_readfirstlane(mx);   // scalar loop bound
        if (mx > 0) {
            float q0 = sq[wave][0][lane];
            for (int s = 0; s < mx; ++s) {
                float q1 = sq[wave][s + 1][lane];  // pad row keeps this in-bounds
                rbf_f2(q0, s < cnt, ff);
                q0 = q1;
            }
        }
    }

    // ---- Epilogue: wave-reduce, block-combine, MLP, one atomic ----
    float fr[N_RBF];
    #pragma unroll
    for (int k = 0; k < 8; ++k) { fr[2 * k] = ff[k].x; fr[2 * k + 1] = ff[k].y; }
    float w4 = treduce(fr, lane);
    if ((lane & 3) == 0) sfeat[wave][lane >> 2] = w4;
    __syncthreads();

    if (tid < 64) {                                // wave 0: both atoms' MLP
        const int a = tid >> 5, h = tid & 31;
        const bool valid = (a0 + a) < n;
        float e = 0.0f;
        if (valid) {
            float acc = sb1[h];
            #pragma unroll
            for (int k = 0; k < N_RBF; ++k) {
                float f = (sfeat[a * 2][k] + sfeat[a * 2 + 1][k]) * UNSC;
                acc = fmaf(f, sW1[k * N_HIDDEN + h], acc);
            }
            float sg = 1.0f / (1.0f + __builtin_amdgcn_exp2f(-acc * LOG2E));
            e = acc * sg * sW2[h];
            if (h == 0) e += b2[0];
        }
        #pragma unroll
        for (int off = 16; off > 0; off >>= 1) e += __shfl_xor(e, off, 64);
        e += __shfl_xor(e, 32, 64);                // combine the two atoms
        if (tid == 0) atomicAdd(out, e);
    }
}

extern "C" void kernel_launch(void* const* d_in, const int* in_sizes, int n_in,
                              void* d_out, int out_size, void* d_ws, size_t ws_size,
                              hipStream_t stream) {
    const float* pos = (const float*)d_in[0];
    const float* W1  = (const float*)d_in[1];
    const float* b1  = (const float*)d_in[2];
    const float* W2  = (const float*)d_in[3];
    const float* b2  = (const float*)d_in[4];
    float* out = (float*)d_out;

    const int n     = in_sizes[0] / 3;
    const int npad  = (n + 511) & ~511;     // halves of x64, iters mult of 4
    const int halfr = npad >> 1;

    float4* ppos = (float4*)d_ws;           // 16*npad bytes of scratch

    pack_kernel<<<(npad + 255) / 256, 256, 0, stream>>>(pos, ppos, out, n, npad);

    const int grid = npad / 2;              // 2 atoms per block
    ag3sr_main<<<grid, BLOCK, 0, stream>>>(ppos, W1, b1, W2, b2, out, n, halfr);
}

// Round 11
// 41.899 us; speedup vs baseline: 1.1555x; 1.0370x over previous
//
#include <hip/hip_runtime.h>

typedef float f2 __attribute__((ext_vector_type(2)));

#define N_RBF 16
#define N_HIDDEN 32
#define BLOCK 256                 // 4 waves = 4 j-quarters of the same 2 atoms
#define NW 4

// Gaussian-grid recurrence (a = 4.5, w = 1/3):
//   r_k = exp(-a (d - k w)^2); r_0 = exp(-a d^2); r_{k+1} = r_k * s_k,
//   s_k = exp(3d - 0.5 - k).  Even/odd chains in the two lanes of an f2:
//   rr = (r_k, r_{k+1}); uu = (s^2 e^-1, s^2 e^-3); step: rr *= uu, uu *= e^-4.
// Chain scaled by 2^80 so r_0 never underflows for d < 5.
#define LOG2E 1.44269504088896340736f
#define NC   (-4.5f * LOG2E)
#define S0A  (3.0f * LOG2E)
#define S0B  (-0.5f * LOG2E)
#define BIAS 80.0f
#define UNSC 8.271806125530277e-25f     // 2^-80
#define C_E1 0.36787944117144233f       // e^-1
#define C_E3 0.049787068367863944f      // e^-3
#define C_E4 0.018315638888734179f      // e^-4

__device__ __forceinline__ float rfl(float x) {
    return __int_as_float(__builtin_amdgcn_readfirstlane(__float_as_int(x)));
}

// Straight-line masked RBF accumulate: no branches, no cross-lane ops.
// d2 clamp keeps s^2 finite for far pairs (s = e^{3d-0.5} overflows at d ~ 26).
__device__ __forceinline__ void rbf_pair(float d2raw, f2 (&ff)[8]) {
    bool ok  = (d2raw > 0.0f) & (d2raw < 25.0f);
    float d2 = ok ? d2raw : 1.0f;
    float d  = __builtin_amdgcn_sqrtf(d2);
    float r0 = __builtin_amdgcn_exp2f(fmaf(d2, NC, BIAS));   // 2^80 * exp(-a d^2)
    float s  = __builtin_amdgcn_exp2f(fmaf(d, S0A, S0B));    // exp(3d - 0.5)
    r0 = ok ? r0 : 0.0f;                                     // kills both chains
    float r1 = r0 * s;
    float s2 = s * s;
    f2 rr; rr.x = r0;        rr.y = r1;
    f2 uu; uu.x = s2 * C_E1; uu.y = s2 * C_E3;
    #pragma unroll
    for (int k = 0; k < 8; ++k) {
        ff[k] += rr;          // v_pk_add_f32
        rr *= uu;             // v_pk_mul_f32
        uu *= C_E4;           // v_pk_mul_f32
    }
}

// Transpose-reduce 16 per-lane partials across 64 lanes.
// Lanes with (lane&3)==0 return the wave-sum of feature k=(lane>>2).
__device__ __forceinline__ float treduce(float (&f)[N_RBF], int lane) {
    float w1r[8];
    #pragma unroll
    for (int k = 0; k < 8; ++k) {
        float lo = f[k], hi = f[k + 8];
        float lo2 = __shfl_xor(lo, 32, 64);
        float hi2 = __shfl_xor(hi, 32, 64);
        w1r[k] = (lane & 32) ? (hi + hi2) : (lo + lo2);
    }
    float w2r[4];
    #pragma unroll
    for (int k = 0; k < 4; ++k) {
        float lo = w1r[k], hi = w1r[k + 4];
        float lo2 = __shfl_xor(lo, 16, 64);
        float hi2 = __shfl_xor(hi, 16, 64);
        w2r[k] = (lane & 16) ? (hi + hi2) : (lo + lo2);
    }
    float w3r[2];
    #pragma unroll
    for (int k = 0; k < 2; ++k) {
        float lo = w2r[k], hi = w2r[k + 2];
        float lo2 = __shfl_xor(lo, 8, 64);
        float hi2 = __shfl_xor(hi, 8, 64);
        w3r[k] = (lane & 8) ? (hi + hi2) : (lo + lo2);
    }
    float lo2 = __shfl_xor(w3r[0], 4, 64);
    float hi2 = __shfl_xor(w3r[1], 4, 64);
    float w4 = (lane & 4) ? (w3r[1] + hi2) : (w3r[0] + lo2);
    w4 += __shfl_xor(w4, 2, 64);
    w4 += __shfl_xor(w4, 1, 64);
    return w4;
}

__global__ __launch_bounds__(256)
void pack_kernel(const float* __restrict__ pos, float4* __restrict__ ppos,
                 float* __restrict__ out, int n, int npad)
{
    int i = blockIdx.x * 256 + threadIdx.x;
    if (i == 0) out[0] = 0.0f;
    if (i < npad) {
        float4 v;
        if (i < n) { v.x = pos[3*i]; v.y = pos[3*i+1]; v.z = pos[3*i+2]; v.w = 0.f; }
        else       { v.x = 1e9f;     v.y = 1e9f;       v.z = 1e9f;       v.w = 0.f; }
        ppos[i] = v;
    }
}

__global__ __launch_bounds__(BLOCK)
void ag3sr_main(const float4* __restrict__ ppos,   // [npad] sentinel-padded
                const float* __restrict__ W1,      // [16,32]
                const float* __restrict__ b1,      // [32]
                const float* __restrict__ W2,      // [32]
                const float* __restrict__ b2,      // [1]
                float* __restrict__ out,           // [1]
                int n, int quarter)                // quarter = npad/4 (mult of 64)
{
    __shared__ float sfeat[NW][2][N_RBF];
    __shared__ float sW1[N_RBF * N_HIDDEN];
    __shared__ float sb1[N_HIDDEN], sW2[N_HIDDEN];

    const int tid  = threadIdx.x;
    const int wave = tid >> 6;                     // = j-segment index
    const int lane = tid & 63;
    const int a0   = blockIdx.x * 2;               // block owns atoms a0, a0+1

    for (int idx = tid; idx < N_RBF * N_HIDDEN; idx += BLOCK) sW1[idx] = W1[idx];
    if (tid < N_HIDDEN) { sb1[tid] = b1[tid]; sW2[tid] = W2[tid]; }

    float4 pa = ppos[a0];
    float4 pb = ppos[a0 + 1];
    const float xa = rfl(pa.x), ya = rfl(pa.y), za = rfl(pa.z);
    const float xb = rfl(pb.x), yb = rfl(pb.y), zb = rfl(pb.z);

    f2 ffA[8], ffB[8];
    #pragma unroll
    for (int k = 0; k < 8; ++k) {
        ffA[k].x = 0.0f; ffA[k].y = 0.0f;
        ffB[k].x = 0.0f; ffB[k].y = 0.0f;
    }

    // ---- Hot loop: straight-line, branchless, 2-deep prefetch ----
    const int jb = wave * quarter;
    const int iters = quarter >> 6;                // 16 for n=4096 (even)

#define PROC(PJ)                                                              \
    {                                                                         \
        float dxa = (PJ).x - xa, dya = (PJ).y - ya, dza = (PJ).z - za;        \
        float qa = fmaf(dza, dza, fmaf(dya, dya, dxa * dxa));                 \
        rbf_pair(qa, ffA);                                                    \
        float dxb = (PJ).x - xb, dyb = (PJ).y - yb, dzb = (PJ).z - zb;        \
        float qb = fmaf(dzb, dzb, fmaf(dyb, dyb, dxb * dxb));                 \
        rbf_pair(qb, ffB);                                                    \
    }

    {
        float4 u0 = ppos[jb + lane];
        float4 u1 = ppos[jb + 64 + lane];
        int it = 0;
        for (; it + 2 < iters; it += 2) {
            float4 n0 = ppos[jb + ((it + 2) << 6) + lane];   // 2-deep prefetch
            float4 n1 = ppos[jb + ((it + 3) << 6) + lane];
            PROC(u0); PROC(u1);
            u0 = n0; u1 = n1;
        }
        PROC(u0); PROC(u1);
    }
#undef PROC

    // ---- Epilogue: wave-reduce both atoms, block-combine, MLP ----
    float fra[N_RBF], frb[N_RBF];
    #pragma unroll
    for (int k = 0; k < 8; ++k) {
        fra[2 * k] = ffA[k].x; fra[2 * k + 1] = ffA[k].y;
        frb[2 * k] = ffB[k].x; frb[2 * k + 1] = ffB[k].y;
    }
    float wA = treduce(fra, lane);
    float wB = treduce(frb, lane);
    if ((lane & 3) == 0) {
        sfeat[wave][0][lane >> 2] = wA;
        sfeat[wave][1][lane >> 2] = wB;
    }
    __syncthreads();

    if (tid < 64) {                                // wave 0: both atoms' MLP
        const int a = tid >> 5, h = tid & 31;
        const bool valid = (a0 + a) < n;
        float e = 0.0f;
        if (valid) {
            float acc = sb1[h];
            #pragma unroll
            for (int k = 0; k < N_RBF; ++k) {
                float f = (sfeat[0][a][k] + sfeat[1][a][k] +
                           sfeat[2][a][k] + sfeat[3][a][k]) * UNSC;
                acc = fmaf(f, sW1[k * N_HIDDEN + h], acc);
            }
            float sg = 1.0f / (1.0f + __builtin_amdgcn_exp2f(-acc * LOG2E));
            e = acc * sg * sW2[h];
            if (h == 0) e += b2[0];
        }
        #pragma unroll
        for (int off = 16; off > 0; off >>= 1) e += __shfl_xor(e, off, 64);
        e += __shfl_xor(e, 32, 64);                // combine the two atoms
        if (tid == 0) atomicAdd(out, e);
    }
}

extern "C" void kernel_launch(void* const* d_in, const int* in_sizes, int n_in,
                              void* d_out, int out_size, void* d_ws, size_t ws_size,
                              hipStream_t stream) {
    const float* pos = (const float*)d_in[0];
    const float* W1  = (const float*)d_in[1];
    const float* b1  = (const float*)d_in[2];
    const float* W2  = (const float*)d_in[3];
    const float* b2  = (const float*)d_in[4];
    float* out = (float*)d_out;

    const int n       = in_sizes[0] / 3;
    const int npad    = (n + 255) & ~255;   // quarters each a multiple of 64
    const int quarter = npad >> 2;

    float4* ppos = (float4*)d_ws;            // 16*npad bytes of scratch

    pack_kernel<<<(npad + 255) / 256, 256, 0, stream>>>(pos, ppos, out, n, npad);

    const int grid = npad / 2;               // 2 atoms per block
    ag3sr_main<<<grid, BLOCK, 0, stream>>>(ppos, W1, b1, W2, b2, out, n, quarter);
}